// Round 6
// baseline (761.089 us; speedup 1.0000x reference)
//
#include <hip/hip_runtime.h>
#include <math.h>

#define N_NODES 10240
#define DIM 256
#define TPB 256
#define NBLK (N_NODES / 128)     // 80 column tiles
#define CAP 1024                 // candidate buffer (expect ~110 for k=30)
#define KMAX 96                  // kept-list capacity (want=31)

typedef _Float16 half8 __attribute__((ext_vector_type(8)));
typedef float f32x4 __attribute__((ext_vector_type(4)));

__device__ __forceinline__ void async_load16(const void* g, void* l) {
  __builtin_amdgcn_global_load_lds(
      (const __attribute__((address_space(1))) unsigned int*)g,
      (__attribute__((address_space(3))) unsigned int*)l, 16, 0, 0);
}

__device__ __forceinline__ unsigned int fmap(float f) {
  unsigned int s = __float_as_uint(f);
  return (s & 0x80000000u) ? ~s : (s | 0x80000000u);
}
__device__ __forceinline__ float funmap(unsigned int m) {
  return __uint_as_float((m & 0x80000000u) ? (m ^ 0x80000000u) : ~m);
}

// ---------------------------------------------------------------------------
// Kernel 1: h = relu(f*w1)*w2 ; e = h/max(||h||,1e-12); split e into fp16
// hi (P0) and scaled lo (P1 = fp16((e-P0)*2^11)). One block per row.
// ---------------------------------------------------------------------------
__global__ __launch_bounds__(256) void norm_split_kernel(
    const float* __restrict__ F, const float* __restrict__ w1,
    const float* __restrict__ w2, _Float16* __restrict__ P0,
    _Float16* __restrict__ P1) {
  int row = blockIdx.x, tid = threadIdx.x;
  __shared__ float red[TPB];
  size_t base = (size_t)row * DIM + tid;
  float h = fmaxf(F[base] * w1[tid], 0.0f) * w2[tid];
  red[tid] = h * h;
  __syncthreads();
  for (int o = TPB / 2; o > 0; o >>= 1) {
    if (tid < o) red[tid] += red[tid + o];
    __syncthreads();
  }
  float e = h / fmaxf(sqrtf(red[0]), 1e-12f);
  _Float16 p0 = (_Float16)e;
  _Float16 p1 = (_Float16)((e - (float)p0) * 2048.0f);
  P0[base] = p0;
  P1[base] = p1;
}

// ---------------------------------------------------------------------------
// Kernel 2: C = E*E^T via fp16x3 MFMA — EXACT R3 STRUCTURE (32KB LDS,
// 3 passes x 4 chunks; R5's 64KB chunk-major fusion regressed: occupancy
// 12->8 waves/CU outweighed barrier savings). NEW: epilogue also emits a
// per-(row, col-tile) max digest (mapped uint) for topk pruning.
// ---------------------------------------------------------------------------
__global__ __launch_bounds__(256) void gemm_mfma_kernel(
    const _Float16* __restrict__ P0, const _Float16* __restrict__ P1,
    float* __restrict__ C, unsigned int* __restrict__ Dg) {
  __shared__ char smem[32768];
  char* AsB = smem;            // 128 rows x 64 halves (16 KB), swizzled
  char* BsB = smem + 16384;

  int tid = threadIdx.x;
  int lane = tid & 63;
  int w = tid >> 6;
  int wr = (w >> 1) * 64;      // wave row quadrant
  int wc = (w & 1) * 64;       // wave col quadrant
  int quad = lane >> 4;
  int mr = lane & 15;
  int rowBase = blockIdx.y * 128;
  int colBase = blockIdx.x * 128;

  // staging: 4 16B units per thread per tile (1024 units = 16KB tile)
  size_t rowOffA[4], rowOffB[4];
  int ldsOff[4];
#pragma unroll
  for (int i = 0; i < 4; ++i) {
    int u = tid + i * 256;
    int m = u >> 3;
    int g = (u & 7) ^ (m & 7);
    ldsOff[i] = u * 16;
    rowOffA[i] = (size_t)(rowBase + m) * DIM + g * 8;
    rowOffB[i] = (size_t)(colBase + m) * DIM + g * 8;
  }

  // fragment ds_read byte offsets: [kstep s][tile t]
  int fOffA[2][4], fOffB[2][4];
#pragma unroll
  for (int s = 0; s < 2; ++s)
#pragma unroll
    for (int t = 0; t < 4; ++t) {
      int g = s * 4 + quad;
      int mA = wr + t * 16 + mr;
      fOffA[s][t] = (mA * 8 + (g ^ (mA & 7))) * 16;
      int mB = wc + t * 16 + mr;
      fOffB[s][t] = (mB * 8 + (g ^ (mB & 7))) * 16;
    }

  f32x4 acc[4][4];
#pragma unroll
  for (int t = 0; t < 4; ++t)
#pragma unroll
    for (int u2 = 0; u2 < 4; ++u2) acc[t][u2] = (f32x4)0.0f;

  const _Float16* Aseg[3] = {P0, P1, P0};
  const _Float16* Bseg[3] = {P1, P0, P0};

  for (int pass = 0; pass < 3; ++pass) {
    if (pass == 2) {
      const float sc = 1.0f / 2048.0f;
#pragma unroll
      for (int t = 0; t < 4; ++t)
#pragma unroll
        for (int u2 = 0; u2 < 4; ++u2)
#pragma unroll
          for (int r = 0; r < 4; ++r) acc[t][u2][r] *= sc;
    }
    const _Float16* Ap = Aseg[pass];
    const _Float16* Bp = Bseg[pass];
    for (int c = 0; c < 4; ++c) {
      int kb = c * 64;
#pragma unroll
      for (int i = 0; i < 4; ++i)
        async_load16(Ap + rowOffA[i] + kb, AsB + ldsOff[i]);
#pragma unroll
      for (int i = 0; i < 4; ++i)
        async_load16(Bp + rowOffB[i] + kb, BsB + ldsOff[i]);
      __syncthreads();
#pragma unroll
      for (int s = 0; s < 2; ++s) {
        half8 af[4], bf[4];
#pragma unroll
        for (int t = 0; t < 4; ++t) {
          af[t] = *(const half8*)(AsB + fOffA[s][t]);
          bf[t] = *(const half8*)(BsB + fOffB[s][t]);
        }
#pragma unroll
        for (int t = 0; t < 4; ++t)
#pragma unroll
          for (int u2 = 0; u2 < 4; ++u2)
            acc[t][u2] = __builtin_amdgcn_mfma_f32_16x16x32_f16(
                af[t], bf[u2], acc[t][u2], 0, 0, 0);
      }
      __syncthreads();
    }
  }

  // ---- digest: per local row (0..127), max over this block's 128 cols
  unsigned int* dls = (unsigned int*)smem;   // LDS free after last barrier
  if (tid < 128) dls[tid] = 0u;              // 0u < any real mapped value
  __syncthreads();
#pragma unroll
  for (int t = 0; t < 4; ++t) {
#pragma unroll
    for (int r = 0; r < 4; ++r) {
      float v = fmaxf(fmaxf(acc[t][0][r], acc[t][1][r]),
                      fmaxf(acc[t][2][r], acc[t][3][r]));
#pragma unroll
      for (int mlane = 1; mlane < 16; mlane <<= 1)
        v = fmaxf(v, __shfl_xor(v, mlane, 64));
      if (mr == 0) atomicMax(&dls[wr + t * 16 + quad * 4 + r], fmap(v));
    }
  }
  __syncthreads();
  if (tid < 128)
    Dg[(size_t)(rowBase + tid) * NBLK + blockIdx.x] = dls[tid];

  // ---- C stores: C/D layout col=lane&15, row=quad*4+reg
#pragma unroll
  for (int t = 0; t < 4; ++t) {
    int gr = rowBase + wr + t * 16 + quad * 4;
#pragma unroll
    for (int u2 = 0; u2 < 4; ++u2) {
      int gc = colBase + wc + u2 * 16 + mr;
      float* cp = C + (size_t)gr * N_NODES + gc;
      cp[0] = acc[t][u2][0];
      cp[(size_t)N_NODES] = acc[t][u2][1];
      cp[(size_t)2 * N_NODES] = acc[t][u2][2];
      cp[(size_t)3 * N_NODES] = acc[t][u2][3];
    }
  }
}

// ---------------------------------------------------------------------------
// Kernel 3: digest-pruned per-row top-(k+1) mask + relu. One block per row.
// L = want-th largest digest entry. Digest entries are actual row elements,
// so >= want elements are >= L => T31 >= L => tiles with max >= L are a
// guaranteed superset of tiles holding top-want entries. Read only those
// tiles (~16KB/row vs 40KB), exact-rank candidates, write zeros + scatter.
// ---------------------------------------------------------------------------
__global__ __launch_bounds__(256) void topk_kernel(
    float* __restrict__ C, const unsigned int* __restrict__ Dg,
    const int* __restrict__ kptr) {
  __shared__ unsigned int dmap[NBLK];
  __shared__ int tlist[NBLK];
  __shared__ unsigned int cu[CAP];
  __shared__ int ci[CAP];
  __shared__ unsigned int bitmap[N_NODES / 32];   // 320 words
  __shared__ float kv[KMAX];
  __shared__ int kc[KMAX];
  __shared__ unsigned int s_nt, s_cnt, s_nk, s_L, s_Tu;
  __shared__ int s_Jcut;

  int tid = threadIdx.x;
  int row = blockIdx.x;
  float* Crow = C + (size_t)row * N_NODES;
  unsigned int want = (unsigned int)(kptr[0] + 1);   // k+1 = 31

  if (tid < NBLK) dmap[tid] = Dg[(size_t)row * NBLK + tid];
  if (tid == 0) { s_nt = 0u; s_cnt = 0u; s_nk = 0u; }
  for (int b = tid; b < N_NODES / 32; b += TPB) bitmap[b] = 0u;
  __syncthreads();

  // L = want-th largest digest (rank by broadcast scan; ties by index)
  if (tid < NBLK) {
    unsigned int v = dmap[tid];
    unsigned int r = 0;
    for (int j = 0; j < NBLK; ++j) {
      unsigned int vj = dmap[j];
      r += (vj > v) || (vj == v && j < tid);
    }
    if (r == want - 1) s_L = v;
  }
  __syncthreads();
  unsigned int L = s_L;

  // selected tiles
  if (tid < NBLK && dmap[tid] >= L) tlist[atomicAdd(&s_nt, 1u)] = tid;
  __syncthreads();
  int nt = (int)s_nt;

  // gather candidates >= L from selected tiles (2 tiles per iteration)
  for (int tb = 0; tb < nt; tb += 2) {
    int which = tb + (tid >> 7);
    if (which < nt) {
      int col = tlist[which] * 128 + (tid & 127);
      unsigned int m = fmap(Crow[col]);
      if (m >= L) {
        unsigned int pos = atomicAdd(&s_cnt, 1u);
        if (pos < CAP) { cu[pos] = m; ci[pos] = col; }
      }
    }
  }
  __syncthreads();
  unsigned int cnt = s_cnt;
  if (cnt > CAP) cnt = CAP;   // random-normal data: overflow prob ~0

  // exact rank among candidates; rank==want-1 -> threshold + index cutoff
  for (unsigned int i = tid; i < cnt; i += TPB) {
    unsigned int ui = cu[i];
    int ii = ci[i];
    unsigned int r = 0;
    for (unsigned int j = 0; j < cnt; ++j) {
      unsigned int uj = cu[j];
      r += (uj > ui) || (uj == ui && ci[j] < ii);
    }
    if (r == want - 1) { s_Tu = ui; s_Jcut = ii; }
  }
  __syncthreads();
  unsigned int Tu = s_Tu;
  int Jcut = s_Jcut;

  // kept list + bitmap
  for (unsigned int i = tid; i < cnt; i += TPB) {
    unsigned int m = cu[i];
    int col = ci[i];
    if ((m > Tu) || (m == Tu && col <= Jcut)) {
      unsigned int p = atomicAdd(&s_nk, 1u);
      if (p < KMAX) {
        kv[p] = fmaxf(funmap(m), 0.0f);   // relu on kept value
        kc[p] = col;
        atomicOr(&bitmap[col >> 5], 1u << (col & 31));
      }
    }
  }
  __syncthreads();
  int nk = (int)s_nk;
  if (nk > KMAX) nk = KMAX;

  // write: zeros everywhere except kept positions (float4-coalesced)
#pragma unroll
  for (int i = 0; i < N_NODES / (TPB * 4); ++i) {
    int j4 = (i * TPB + tid) * 4;
    unsigned int bits = (bitmap[j4 >> 5] >> (j4 & 31)) & 0xFu;
    float4 o = make_float4(0.0f, 0.0f, 0.0f, 0.0f);
    if (bits) {
      float* oc = (float*)&o;
#pragma unroll
      for (int c = 0; c < 4; ++c) {
        if ((bits >> c) & 1u) {
          int col = j4 + c;
          for (int s = 0; s < nk; ++s)
            if (kc[s] == col) { oc[c] = kv[s]; break; }
        }
      }
    }
    *(float4*)&Crow[j4] = o;
  }
}

// ---------------------------------------------------------------------------
extern "C" void kernel_launch(void* const* d_in, const int* in_sizes, int n_in,
                              void* d_out, int out_size, void* d_ws, size_t ws_size,
                              hipStream_t stream) {
  const float* F  = (const float*)d_in[0];
  const float* w1 = (const float*)d_in[1];
  const float* w2 = (const float*)d_in[2];
  const int*   kp = (const int*)d_in[3];
  float* C = (float*)d_out;
  _Float16* P0 = (_Float16*)d_ws;                         // 5.24 MB
  _Float16* P1 = P0 + (size_t)N_NODES * DIM;              // 5.24 MB
  unsigned int* Dg = (unsigned int*)(P1 + (size_t)N_NODES * DIM);  // 3.28 MB

  norm_split_kernel<<<N_NODES, DIM, 0, stream>>>(F, w1, w2, P0, P1);

  dim3 grid(N_NODES / 128, N_NODES / 128);                // 80 x 80
  gemm_mfma_kernel<<<grid, 256, 0, stream>>>(P0, P1, C, Dg);

  topk_kernel<<<N_NODES, TPB, 0, stream>>>(C, Dg, kp);
}

// Round 7
// 666.945 us; speedup vs baseline: 1.1412x; 1.1412x over previous
//
#include <hip/hip_runtime.h>
#include <math.h>

#define N_NODES 10240
#define DIM 256
#define TPB 256
#define CAP 1536

typedef _Float16 half8 __attribute__((ext_vector_type(8)));
typedef _Float16 half4 __attribute__((ext_vector_type(4)));
typedef float f32x4 __attribute__((ext_vector_type(4)));

__device__ __forceinline__ void async_load16(const void* g, void* l) {
  __builtin_amdgcn_global_load_lds(
      (const __attribute__((address_space(1))) unsigned int*)g,
      (__attribute__((address_space(3))) unsigned int*)l, 16, 0, 0);
}

// ---------------------------------------------------------------------------
// Kernel 1 (rewritten): one WAVE per row, barrier-free.
// float4 loads (lane l owns cols 4l..4l+3), 6-hop shfl_xor butterfly for
// ||h||^2, packed half4 stores of P0 / P1 (fp16x3 split: p1=(e-p0)*2^11).
// ---------------------------------------------------------------------------
__global__ __launch_bounds__(256) void norm_split_kernel(
    const float* __restrict__ F, const float* __restrict__ w1,
    const float* __restrict__ w2, _Float16* __restrict__ P0,
    _Float16* __restrict__ P1) {
  int wave = threadIdx.x >> 6;
  int lane = threadIdx.x & 63;
  int row = blockIdx.x * 4 + wave;
  size_t base = (size_t)row * DIM + lane * 4;

  float4 f = *(const float4*)&F[base];
  float4 a = *(const float4*)&w1[lane * 4];
  float4 b = *(const float4*)&w2[lane * 4];
  float h0 = fmaxf(f.x * a.x, 0.0f) * b.x;
  float h1 = fmaxf(f.y * a.y, 0.0f) * b.y;
  float h2 = fmaxf(f.z * a.z, 0.0f) * b.z;
  float h3 = fmaxf(f.w * a.w, 0.0f) * b.w;

  float ss = h0 * h0 + h1 * h1 + h2 * h2 + h3 * h3;
#pragma unroll
  for (int o = 1; o < 64; o <<= 1) ss += __shfl_xor(ss, o, 64);
  float inv = 1.0f / fmaxf(sqrtf(ss), 1e-12f);

  float e[4] = {h0 * inv, h1 * inv, h2 * inv, h3 * inv};
  half4 p0, p1;
#pragma unroll
  for (int c = 0; c < 4; ++c) {
    _Float16 hi = (_Float16)e[c];
    p0[c] = hi;
    p1[c] = (_Float16)((e[c] - (float)hi) * 2048.0f);
  }
  *(half4*)&P0[base] = p0;
  *(half4*)&P1[base] = p1;
}

// ---------------------------------------------------------------------------
// Kernel 2: C = E*E^T via fp16x3 MFMA — EXACT R3 STRUCTURE (best known:
// 32KB LDS, 3 passes x 4 chunks, single accumulator). R4 mirror-store,
// R5 64KB chunk-major fusion, and R6 digest epilogue ALL regressed —
// never trade this kernel's occupancy/streaming for traffic or barriers.
// ---------------------------------------------------------------------------
__global__ __launch_bounds__(256) void gemm_mfma_kernel(
    const _Float16* __restrict__ P0, const _Float16* __restrict__ P1,
    float* __restrict__ C) {
  __shared__ char smem[32768];
  char* AsB = smem;            // 128 rows x 64 halves (16 KB), swizzled
  char* BsB = smem + 16384;

  int tid = threadIdx.x;
  int lane = tid & 63;
  int w = tid >> 6;
  int wr = (w >> 1) * 64;      // wave row quadrant
  int wc = (w & 1) * 64;       // wave col quadrant
  int quad = lane >> 4;
  int mr = lane & 15;
  int rowBase = blockIdx.y * 128;
  int colBase = blockIdx.x * 128;

  // staging: 4 16B units per thread per tile (1024 units = 16KB tile)
  size_t rowOffA[4], rowOffB[4];
  int ldsOff[4];
#pragma unroll
  for (int i = 0; i < 4; ++i) {
    int u = tid + i * 256;
    int m = u >> 3;
    int g = (u & 7) ^ (m & 7);
    ldsOff[i] = u * 16;
    rowOffA[i] = (size_t)(rowBase + m) * DIM + g * 8;
    rowOffB[i] = (size_t)(colBase + m) * DIM + g * 8;
  }

  // fragment ds_read byte offsets: [kstep s][tile t]
  int fOffA[2][4], fOffB[2][4];
#pragma unroll
  for (int s = 0; s < 2; ++s)
#pragma unroll
    for (int t = 0; t < 4; ++t) {
      int g = s * 4 + quad;
      int mA = wr + t * 16 + mr;
      fOffA[s][t] = (mA * 8 + (g ^ (mA & 7))) * 16;
      int mB = wc + t * 16 + mr;
      fOffB[s][t] = (mB * 8 + (g ^ (mB & 7))) * 16;
    }

  f32x4 acc[4][4];
#pragma unroll
  for (int t = 0; t < 4; ++t)
#pragma unroll
    for (int u2 = 0; u2 < 4; ++u2) acc[t][u2] = (f32x4)0.0f;

  const _Float16* Aseg[3] = {P0, P1, P0};
  const _Float16* Bseg[3] = {P1, P0, P0};

  for (int pass = 0; pass < 3; ++pass) {
    if (pass == 2) {
      const float sc = 1.0f / 2048.0f;
#pragma unroll
      for (int t = 0; t < 4; ++t)
#pragma unroll
        for (int u2 = 0; u2 < 4; ++u2)
#pragma unroll
          for (int r = 0; r < 4; ++r) acc[t][u2][r] *= sc;
    }
    const _Float16* Ap = Aseg[pass];
    const _Float16* Bp = Bseg[pass];
    for (int c = 0; c < 4; ++c) {
      int kb = c * 64;
#pragma unroll
      for (int i = 0; i < 4; ++i)
        async_load16(Ap + rowOffA[i] + kb, AsB + ldsOff[i]);
#pragma unroll
      for (int i = 0; i < 4; ++i)
        async_load16(Bp + rowOffB[i] + kb, BsB + ldsOff[i]);
      __syncthreads();
#pragma unroll
      for (int s = 0; s < 2; ++s) {
        half8 af[4], bf[4];
#pragma unroll
        for (int t = 0; t < 4; ++t) {
          af[t] = *(const half8*)(AsB + fOffA[s][t]);
          bf[t] = *(const half8*)(BsB + fOffB[s][t]);
        }
#pragma unroll
        for (int t = 0; t < 4; ++t)
#pragma unroll
          for (int u2 = 0; u2 < 4; ++u2)
            acc[t][u2] = __builtin_amdgcn_mfma_f32_16x16x32_f16(
                af[t], bf[u2], acc[t][u2], 0, 0, 0);
      }
      __syncthreads();
    }
  }

  // epilogue: C/D layout col=lane&15, row=quad*4+reg
#pragma unroll
  for (int t = 0; t < 4; ++t) {
    int gr = rowBase + wr + t * 16 + quad * 4;
#pragma unroll
    for (int u2 = 0; u2 < 4; ++u2) {
      int gc = colBase + wc + u2 * 16 + mr;
      float* cp = C + (size_t)gr * N_NODES + gc;
      cp[0] = acc[t][u2][0];
      cp[(size_t)N_NODES] = acc[t][u2][1];
      cp[(size_t)2 * N_NODES] = acc[t][u2][2];
      cp[(size_t)3 * N_NODES] = acc[t][u2][3];
    }
  }
}

// ---------------------------------------------------------------------------
// Kernel 3: per-row top-(k+1) mask + relu, in place — EXACT R3 version
// (register-resident full-row scan; streaming reads/writes at ~5.6 TB/s).
// R6's digest-pruned variant regressed: scattered gathers lost to streaming.
// ---------------------------------------------------------------------------
__global__ __launch_bounds__(256) void topk_kernel(
    float* __restrict__ C, const int* __restrict__ kptr) {
  constexpr int EPT = N_NODES / TPB;   // 40
  constexpr int NV4 = EPT / 4;         // 10
  __shared__ unsigned int lm[TPB];
  __shared__ unsigned int cu[CAP];
  __shared__ int ci[CAP];
  __shared__ unsigned int s_cnt, s_L31, s_Tu;
  __shared__ int s_Jcut;

  int tid = threadIdx.x;
  float* Crow = C + (size_t)blockIdx.x * N_NODES;
  unsigned int want = (unsigned int)(kptr[0] + 1);   // k+1

  unsigned int u[EPT];
  unsigned int lmax = 0u;
#pragma unroll
  for (int i = 0; i < NV4; ++i) {
    float4 v = *(const float4*)&Crow[(i * TPB + tid) * 4];
    float fv[4] = {v.x, v.y, v.z, v.w};
#pragma unroll
    for (int c = 0; c < 4; ++c) {
      unsigned int s = __float_as_uint(fv[c]);
      unsigned int m = (s & 0x80000000u) ? ~s : (s | 0x80000000u);
      u[i * 4 + c] = m;
      lmax = (m > lmax) ? m : lmax;
    }
  }
  lm[tid] = lmax;
  if (tid == 0) s_cnt = 0u;
  __syncthreads();

  // L31 = want-th largest of the 256 local maxima (broadcast LDS scan)
  {
    unsigned int r = 0;
    for (int j = 0; j < TPB; ++j) {
      unsigned int vj = lm[j];
      r += (vj > lmax) || (vj == lmax && j < tid);
    }
    if (r == want - 1) s_L31 = lmax;
  }
  __syncthreads();
  unsigned int L31 = s_L31;

  // gather candidates >= L31 (guaranteed >= want exist)
#pragma unroll
  for (int i = 0; i < EPT; ++i) {
    if (u[i] >= L31) {
      unsigned int pos = atomicAdd(&s_cnt, 1u);
      if (pos < CAP) {
        cu[pos] = u[i];
        ci[pos] = ((i / 4) * TPB + tid) * 4 + (i % 4);
      }
    }
  }
  __syncthreads();
  unsigned int c_total = s_cnt;

  if (c_total <= CAP) {
    for (unsigned int i = tid; i < c_total; i += TPB) {
      unsigned int ui = cu[i];
      int ii = ci[i];
      unsigned int r = 0;
      for (unsigned int j = 0; j < c_total; ++j) {
        unsigned int uj = cu[j];
        r += (uj > ui) || (uj == ui && ci[j] < ii);
      }
      if (r == want - 1) { s_Tu = ui; s_Jcut = ii; }
    }
    __syncthreads();
  } else {
    // degenerate fallback: bit-exact bisection on mapped value
    unsigned int lo = 0u, hi = 0xFFFFFFFFu;
    while (lo < hi) {
      unsigned int mid = lo + ((hi - lo) >> 1);
      unsigned int cnt = 0;
#pragma unroll
      for (int i = 0; i < EPT; ++i) cnt += (u[i] > mid) ? 1u : 0u;
      lm[tid] = cnt;
      __syncthreads();
      for (int o = TPB / 2; o > 0; o >>= 1) {
        if (tid < o) lm[tid] += lm[tid + o];
        __syncthreads();
      }
      unsigned int gcnt = lm[0];
      __syncthreads();
      if (gcnt < want) hi = mid; else lo = mid + 1u;
    }
    unsigned int Tu = lo;
    unsigned int cnt = 0;
#pragma unroll
    for (int i = 0; i < EPT; ++i) cnt += (u[i] > Tu) ? 1u : 0u;
    lm[tid] = cnt;
    __syncthreads();
    for (int o = TPB / 2; o > 0; o >>= 1) {
      if (tid < o) lm[tid] += lm[tid + o];
      __syncthreads();
    }
    unsigned int need = want - lm[0];
    __syncthreads();
    int jlo = 0, jhi = N_NODES - 1;
    while (jlo < jhi) {
      int jmid = (jlo + jhi) >> 1;
      unsigned int cc = 0;
#pragma unroll
      for (int i = 0; i < EPT; ++i) {
        int jj = ((i / 4) * TPB + tid) * 4 + (i % 4);
        cc += (u[i] == Tu && jj <= jmid) ? 1u : 0u;
      }
      lm[tid] = cc;
      __syncthreads();
      for (int o = TPB / 2; o > 0; o >>= 1) {
        if (tid < o) lm[tid] += lm[tid + o];
        __syncthreads();
      }
      unsigned int tot = lm[0];
      __syncthreads();
      if (tot >= need) jhi = jmid; else jlo = jmid + 1;
    }
    if (tid == 0) { s_Tu = Tu; s_Jcut = jlo; }
    __syncthreads();
  }

  unsigned int Tu = s_Tu;
  int Jcut = s_Jcut;

#pragma unroll
  for (int i = 0; i < NV4; ++i) {
    float out[4];
#pragma unroll
    for (int c = 0; c < 4; ++c) {
      unsigned int m = u[i * 4 + c];
      int j = (i * TPB + tid) * 4 + c;
      bool keep = (m > Tu) || (m == Tu && j <= Jcut);
      float v = __uint_as_float((m & 0x80000000u) ? (m ^ 0x80000000u) : ~m);
      out[c] = (keep && v > 0.0f) ? v : 0.0f;
    }
    *(float4*)&Crow[(i * TPB + tid) * 4] =
        make_float4(out[0], out[1], out[2], out[3]);
  }
}

// ---------------------------------------------------------------------------
extern "C" void kernel_launch(void* const* d_in, const int* in_sizes, int n_in,
                              void* d_out, int out_size, void* d_ws, size_t ws_size,
                              hipStream_t stream) {
  const float* F  = (const float*)d_in[0];
  const float* w1 = (const float*)d_in[1];
  const float* w2 = (const float*)d_in[2];
  const int*   kp = (const int*)d_in[3];
  float* C = (float*)d_out;
  _Float16* P0 = (_Float16*)d_ws;                    // N*D fp16 = 5.24 MB
  _Float16* P1 = P0 + (size_t)N_NODES * DIM;         // N*D fp16 = 5.24 MB

  norm_split_kernel<<<N_NODES / 4, TPB, 0, stream>>>(F, w1, w2, P0, P1);

  dim3 grid(N_NODES / 128, N_NODES / 128);           // 80 x 80
  gemm_mfma_kernel<<<grid, 256, 0, stream>>>(P0, P1, C);

  topk_kernel<<<N_NODES, TPB, 0, stream>>>(C, kp);
}